// Round 14
// baseline (246.855 us; speedup 1.0000x reference)
//
#include <hip/hip_runtime.h>
#include <hip/hip_bf16.h>
#include <math.h>

#define EPSV 1e-6f
#define LAMBDAV 1e-3f
#define LN_2PI 1.8378770664093453f

__device__ __forceinline__ float bflo(unsigned int u) {
    union { unsigned int i; float f; } x; x.i = u << 16; return x.f;
}
__device__ __forceinline__ float bfhi(unsigned int u) {
    union { unsigned int i; float f; } x; x.i = u & 0xffff0000u; return x.f;
}
__device__ __forceinline__ unsigned short f2bf(float f) {
    __hip_bfloat16 h = __float2bfloat16(f);
    return *(unsigned short*)&h;
}

typedef __attribute__((ext_vector_type(8))) short s8v;
typedef __attribute__((ext_vector_type(4))) float f4v;
typedef __attribute__((ext_vector_type(2))) int i2v;

// DPP lane-permute move (VALU-latency cross-lane, no LDS pipe).
template<int CTRL>
__device__ __forceinline__ float dpp_mv(float x) {
    return __int_as_float(__builtin_amdgcn_update_dpp(
        0, __float_as_int(x), CTRL, 0xF, 0xF, true));
}
__device__ __forceinline__ float x16_sum(float x) {
#if __has_builtin(__builtin_amdgcn_permlane16_swap)
    i2v r = __builtin_amdgcn_permlane16_swap(__float_as_int(x), __float_as_int(x), false, false);
    return __int_as_float(r.x) + __int_as_float(r.y);
#else
    return x + __int_as_float(__builtin_amdgcn_ds_swizzle(__float_as_int(x), 0x401F));
#endif
}
__device__ __forceinline__ float x16_max(float x) {
#if __has_builtin(__builtin_amdgcn_permlane16_swap)
    i2v r = __builtin_amdgcn_permlane16_swap(__float_as_int(x), __float_as_int(x), false, false);
    return fmaxf(__int_as_float(r.x), __int_as_float(r.y));
#else
    return fmaxf(x, __int_as_float(__builtin_amdgcn_ds_swizzle(__float_as_int(x), 0x401F)));
#endif
}
__device__ __forceinline__ float xhalf_sum(float x) {
#if __has_builtin(__builtin_amdgcn_permlane32_swap)
    i2v r = __builtin_amdgcn_permlane32_swap(__float_as_int(x), __float_as_int(x), false, false);
    return __int_as_float(r.x) + __int_as_float(r.y);
#else
    return x + __shfl_xor(x, 32, 64);
#endif
}
__device__ __forceinline__ float red_max32(float x) {
    x = fmaxf(x, dpp_mv<0xB1>(x));    // quad_perm [1,0,3,2]  (xor 1)
    x = fmaxf(x, dpp_mv<0x4E>(x));    // quad_perm [2,3,0,1]  (xor 2)
    x = fmaxf(x, dpp_mv<0x124>(x));   // row_ror:4
    x = fmaxf(x, dpp_mv<0x128>(x));   // row_ror:8
    return x16_max(x);
}
__device__ __forceinline__ float red_sum32(float x) {
    x += dpp_mv<0xB1>(x);
    x += dpp_mv<0x4E>(x);
    x += dpp_mv<0x124>(x);
    x += dpp_mv<0x128>(x);
    return x16_sum(x);
}
__device__ __forceinline__ float red_sum16(float x) {
    x += dpp_mv<0xB1>(x);
    x += dpp_mv<0x4E>(x);
    x += dpp_mv<0x124>(x);
    x += dpp_mv<0x128>(x);
    return x;
}
__device__ __forceinline__ float g_agent_load(const float* p) {
    return __hip_atomic_load(p, __ATOMIC_RELAXED, __HIP_MEMORY_SCOPE_AGENT);
}

// Kernel 1: MFMA conv, M-split: 576 blocks = (i2, cq-half), ~5 blocks/CU.
// LDS-transposed epilogue (R12, verified). w stage vectorized to float4.
__global__ __launch_bounds__(256)
void conv_v_kernel(const float* __restrict__ x, const float* __restrict__ w,
                   __hip_bfloat16* __restrict__ vout, unsigned int* __restrict__ cnt)
{
    __shared__ unsigned short wb[256 * 40];  // [cq_local][p pad40]
    __shared__ unsigned short pb[128 * 40];  // [n][p pad40]
    __shared__ unsigned short st[16 * 264];  // [n_local][cq_local pad264]

    const int bid = blockIdx.x;
    const int i2  = bid >> 1;
    const int mh  = bid & 1;                 // cq half: [mh*256, mh*256+256)
    const int tid = threadIdx.x;

    if (bid == 0 && tid < 128) cnt[tid] = 0;  // zero s2's last-block counters

    // zero k=16..31 padding (mfma reads k<32)
    for (int u = tid; u < 256 * 8; u += 256) {
        int r = u >> 3, j = u & 7;
        *(unsigned int*)&wb[r * 40 + 16 + j * 2] = 0;
    }
    for (int u = tid; u < 128 * 8; u += 256) {
        int r = u >> 3, j = u & 7;
        *(unsigned int*)&pb[r * 40 + 16 + j * 2] = 0;
    }
    // stage w fp32 -> wb bf16, vectorized: 4x float4 per thread
    {
        const float* wsrc = w + (size_t)i2 * 8192 + mh * 4096;
        #pragma unroll
        for (int uu = 0; uu < 4; ++uu) {
            int idx = (uu * 256 + tid) * 4;        // cl*256 + p*16 + q, q%4==0
            float4 f = *(const float4*)&wsrc[idx];
            int cl = idx >> 8, p = (idx >> 4) & 15, q = idx & 15;
            wb[(cl * 16 + q + 0) * 40 + p] = f2bf(f.x);
            wb[(cl * 16 + q + 1) * 40 + p] = f2bf(f.y);
            wb[(cl * 16 + q + 2) * 40 + p] = f2bf(f.z);
            wb[(cl * 16 + q + 3) * 40 + p] = f2bf(f.w);
        }
    }
    // fused gather: pb[nn][p] from x via reference reshape scramble
    #pragma unroll
    for (int u = 0; u < 8; ++u) {
        int idx = u * 256 + tid;               // nn*16 + p
        int nn = idx >> 4, p = idx & 15;
        int e  = i2 * 16 + p;
        int k2 = e >> 9, c2 = e & 511;
        int f  = k2 * 544 + c2;
        int ci = f / 9, kk = f - ci * 9;
        int bi = nn >> 6, oi = (nn >> 3) & 7, oj = nn & 7;
        int row = 2 * oi + kk / 3 - 1;
        int col = 2 * oj + (kk - (kk / 3) * 3) - 1;
        float val = 0.f;
        if ((unsigned)row < 16u && (unsigned)col < 16u)
            val = x[((bi * 16 + row) * 16 + col) * 544 + ci];
        pb[nn * 40 + p] = f2bf(val);
    }
    __syncthreads();

    const int lane = tid & 63;
    const int wv   = tid >> 6;
    const int l16  = lane & 15;
    const int quad = lane >> 4;
    const int cq0l = wv * 64;                  // local cq base of this wave

    s8v afrag[4], bfrag[8];
    #pragma unroll
    for (int mt = 0; mt < 4; ++mt)
        afrag[mt] = *(const s8v*)&wb[(cq0l + mt * 16 + l16) * 40 + quad * 8];
    #pragma unroll
    for (int nt = 0; nt < 8; ++nt)
        bfrag[nt] = *(const s8v*)&pb[(nt * 16 + l16) * 40 + quad * 8];

    const int srow = tid >> 4;                 // readout row 0..15
    const int schk = tid & 15;                 // readout 16-short chunk
    #pragma unroll
    for (int nt = 0; nt < 8; ++nt) {
        #pragma unroll
        for (int mt = 0; mt < 4; ++mt) {
            f4v acc = {0.f, 0.f, 0.f, 0.f};
            acc = __builtin_amdgcn_mfma_f32_16x16x32_bf16(afrag[mt], bfrag[nt], acc, 0, 0, 0);
            int ccol = cq0l + mt * 16 + quad * 4;   // 0..255 within mh half
            unsigned int lo = f2bf(acc[0]) | ((unsigned int)f2bf(acc[1]) << 16);
            unsigned int hi = f2bf(acc[2]) | ((unsigned int)f2bf(acc[3]) << 16);
            uint2 pk; pk.x = lo; pk.y = hi;
            *(uint2*)&st[l16 * 264 + ccol] = pk;    // row n=l16, 8B aligned
        }
        __syncthreads();
        // coalesced writeback: 16 threads/row x 32 B each = 512 B run
        {
            uint4 d0 = *(const uint4*)&st[srow * 264 + schk * 16];
            uint4 d1 = *(const uint4*)&st[srow * 264 + schk * 16 + 8];
            int nl = nt * 16 + srow;
            unsigned short* dst = (unsigned short*)vout
                + ((size_t)nl * 288 + i2) * 512 + mh * 256 + schk * 16;
            *(uint4*)dst = d0;
            *(uint4*)(dst + 8) = d1;
        }
        __syncthreads();
    }
}

// Kernel 2: one EM sweep (iteration t), grid 768 = (n, h in 0..5), 512 thr.
// t=0 computes fct from x and caches it in gfct; t>0 loads it coalesced.
// t=2 fuses the old em_final via the last-block pattern: threadfence +
// syncthreads + tid0 ACQ_REL atomicAdd(cnt[n]); the 6th arrival finalizes n
// with AGENT-relaxed gpart loads (single end-of-kernel fence -- NOT R3's
// per-pair acquire spin that flushed L2 repeatedly).
__global__ __launch_bounds__(512)
void em_sweep_kernel(const float* __restrict__ x,
                     const unsigned short* __restrict__ v,   // [n][i][cq] bf16
                     const float* __restrict__ beta_u,
                     const float* __restrict__ beta_a,
                     float* __restrict__ gpart,              // [t][n][6][1088]
                     float* __restrict__ gfct,               // [n][288]
                     unsigned int* __restrict__ cnt,         // [n]
                     float* __restrict__ out,
                     const int t)
{
    __shared__ float fct_s[288];            // a/(a+eps)
    __shared__ float red_s[8 * 64 * 17];    // [wave][lane][s0|s1[8]|s2[8]]
    __shared__ float mu_s[32 * 17];
    __shared__ float i2ss_s[32 * 17];
    __shared__ float kc_s[32];
    __shared__ float aout_s[32];
    __shared__ unsigned int last_s;

    const int bid = blockIdx.x;
    const int n   = bid & 127;
    const int h   = bid >> 7;               // 0..5, rows [h*48, h*48+48)
    const int tid = threadIdx.x;
    const int bi = n >> 6, oi = (n >> 3) & 7, oj = n & 7;

    if (t == 0) {
        if (tid < 288) {
            int k2 = tid >> 5;
            int c2 = 512 + (tid & 31);
            int f  = k2 * 544 + c2;
            int ci = f / 9;
            int kk = f - ci * 9;
            int row = 2 * oi + kk / 3 - 1;
            int col = 2 * oj + (kk - (kk / 3) * 3) - 1;
            float a = 0.f;
            if ((unsigned)row < 16u && (unsigned)col < 16u)
                a = x[((bi * 16 + row) * 16 + col) * 544 + ci];
            float fc = a / (a + EPSV);   // sum_c r*a == a -> rr = softmax * fct
            fct_s[tid] = fc;
            if (h == 0) gfct[n * 288 + tid] = fc;   // cache for t=1,2
        }
    } else {
        if (tid < 288) fct_s[tid] = gfct[n * 288 + tid];
    }

    // finalize previous iteration's stats from all 6 slices (t>0)
    if (t > 0) {
        const int c2 = tid >> 4, q2 = tid & 15;
        const float* pa = gpart + ((size_t)(t - 1) * 128 + n) * 6 * 1088;
        float S1 = 0.f, S2 = 0.f, S0 = 0.f;
        #pragma unroll
        for (int j = 0; j < 6; ++j) {
            S1 += pa[j * 1088 + tid];
            S2 += pa[j * 1088 + 512 + tid];
            S0 += pa[j * 1088 + 1024 + c2];
        }
        float invr = 1.0f / (S0 + EPSV);
        float w0  = S0 * invr;
        float m   = S1 * invr;
        float s2p = S2 * invr;
        float sig = s2p - m * m * (2.0f - w0);   // == sum coeff*(v-mu)^2
        sig = fmaxf(sig + EPSV, 1e-4f);
        float hl = 0.5f * logf(sig);
        mu_s[c2 * 17 + q2]   = m;
        i2ss_s[c2 * 17 + q2] = 1.0f / (2.0f * sig);
        float shl = red_sum16(hl);
        if (q2 == 0) {
            float bu  = beta_u[c2];
            float cs  = (16.0f * bu + shl) * S0;
            float arg = LAMBDAV * (beta_a[c2] - cs);
            float ao  = 1.0f / (1.0f + expf(-arg));
            ao = fminf(fmaxf(ao, 1e-4f), 1.0f - 1e-4f);
            kc_s[c2]  = logf(ao + EPSV) - shl - 8.0f * LN_2PI;
        }
    }
    __syncthreads();

    const unsigned short* vb = v + (size_t)n * 288 * 512;
    const int wv   = tid >> 6;      // wave 0..7
    const int lane = tid & 63;
    const int c    = lane & 31;
    const int qh   = lane >> 5;     // q-half 0/1
    const int qb   = qh * 8;
    const unsigned short* base = vb + c * 16 + qb;

    float mu8[8], is8[8], kcv = 0.f;
    if (t > 0) {
        #pragma unroll
        for (int j = 0; j < 8; ++j) {
            mu8[j] = mu_s[c * 17 + qb + j];
            is8[j] = i2ss_s[c * 17 + qb + j];
        }
        kcv = kc_s[c];
    }

    float s0 = 0.f, s1[8], s2[8];
    #pragma unroll
    for (int j = 0; j < 8; ++j) { s1[j] = 0.f; s2[j] = 0.f; }

    const int kofs = h * 48;         // rows kofs + kp*16 + {wv, wv+8}, kp<3

    // prefetch pair 0
    uint4 ua = *(const uint4*)(base + (size_t)(kofs + 0 + wv) * 512);
    uint4 ub = *(const uint4*)(base + (size_t)(kofs + 8 + wv) * 512);

    #pragma unroll
    for (int kp = 0; kp < 3; ++kp) {
        const int ia = kofs + kp * 16 + wv;
        const int ib = ia + 8;
        uint4 una = ua, unb = ub;
        if (kp < 2) {   // issue next pair before the compute chain
            una = *(const uint4*)(base + (size_t)(ia + 16) * 512);
            unb = *(const uint4*)(base + (size_t)(ia + 24) * 512);
        }
        float va[8], vvb[8];
        va[0] = bflo(ua.x); va[1] = bfhi(ua.x);
        va[2] = bflo(ua.y); va[3] = bfhi(ua.y);
        va[4] = bflo(ua.z); va[5] = bfhi(ua.z);
        va[6] = bflo(ua.w); va[7] = bfhi(ua.w);
        vvb[0] = bflo(ub.x); vvb[1] = bfhi(ub.x);
        vvb[2] = bflo(ub.y); vvb[3] = bfhi(ub.y);
        vvb[4] = bflo(ub.z); vvb[5] = bfhi(ub.z);
        vvb[6] = bflo(ub.w); vvb[7] = bfhi(ub.w);

        float rra, rrb;
        if (t == 0) {
            rra = fct_s[ia] * 0.03125f;
            rrb = fct_s[ib] * 0.03125f;
        } else {
            float pa = 0.f, pb2 = 0.f;
            #pragma unroll
            for (int j = 0; j < 8; ++j) {
                float da = va[j] - mu8[j];
                float db = vvb[j] - mu8[j];
                pa  += da * da * is8[j];
                pb2 += db * db * is8[j];
            }
            pa  = xhalf_sum(pa);      // combine q-halves (xor32, VALU)
            pb2 = xhalf_sum(pb2);
            float acca = kcv - pa;
            float accb = kcv - pb2;
            float mxa = red_max32(acca);
            float mxb = red_max32(accb);
            float ea = __expf(acca - mxa);
            float eb = __expf(accb - mxb);
            float sa = red_sum32(ea);
            float sb = red_sum32(eb);
            rra = (ea / sa) * fct_s[ia];
            rrb = (eb / sb) * fct_s[ib];
        }

        s0 += rra + rrb;
        #pragma unroll
        for (int j = 0; j < 8; ++j) {
            s1[j] += rra * va[j] + rrb * vvb[j];
            s2[j] += rra * va[j] * va[j] + rrb * vvb[j] * vvb[j];
        }
        ua = una; ub = unb;
    }

    // per-wave partials -> LDS (stride 17: 2-way bank alias = free)
    {
        float* dst = &red_s[(wv * 64 + lane) * 17];
        dst[0] = s0;
        #pragma unroll
        for (int j = 0; j < 8; ++j) { dst[1 + j] = s1[j]; dst[9 + j] = s2[j]; }
    }
    __syncthreads();

    // final 8-way reduce -> this block's own gpart slot (plain stores)
    {
        const int c2 = tid >> 4, q2 = tid & 15;
        const int qh2 = q2 >> 3, j2 = q2 & 7;
        float S0 = 0.f, S1 = 0.f, S2 = 0.f;
        #pragma unroll
        for (int wvi = 0; wvi < 8; ++wvi) {
            S0 += red_s[(wvi * 64 + c2) * 17];
            const float* sp = &red_s[(wvi * 64 + qh2 * 32 + c2) * 17];
            S1 += sp[1 + j2];
            S2 += sp[9 + j2];
        }
        float* po = gpart + (((size_t)t * 128 + n) * 6 + h) * 1088;
        po[tid] = S1;
        po[512 + tid] = S2;
        if (q2 == 0) po[1024 + c2] = S0;
    }

    // t=2: fused finalize via last-block pattern (replaces em_final launch)
    if (t == 2) {
        __threadfence();           // publish this block's gpart[2] agent-wide
        __syncthreads();
        if (tid == 0) {
            unsigned int old = __hip_atomic_fetch_add(
                &cnt[n], 1u, __ATOMIC_ACQ_REL, __HIP_MEMORY_SCOPE_AGENT);
            last_s = (old == 5u) ? 1u : 0u;
        }
        __syncthreads();
        if (last_s) {
            const int c2 = tid >> 4, q2 = tid & 15;
            const float* pa = gpart + ((size_t)2 * 128 + n) * 6 * 1088;
            float S1 = 0.f, S2 = 0.f, S0 = 0.f;
            #pragma unroll
            for (int j = 0; j < 6; ++j) {
                S1 += g_agent_load(pa + j * 1088 + tid);
                S2 += g_agent_load(pa + j * 1088 + 512 + tid);
                S0 += g_agent_load(pa + j * 1088 + 1024 + c2);
            }
            float invr = 1.0f / (S0 + EPSV);
            float w0  = S0 * invr;
            float m   = S1 * invr;
            float s2p = S2 * invr;
            float sig = s2p - m * m * (2.0f - w0);
            sig = fmaxf(sig + EPSV, 1e-4f);
            float hl = 0.5f * logf(sig);
            float shl = red_sum16(hl);
            if (q2 == 0) {
                float bu  = beta_u[c2];
                float cs  = (16.0f * bu + shl) * S0;
                float arg = LAMBDAV * (beta_a[c2] - cs);
                float ao  = 1.0f / (1.0f + expf(-arg));
                ao = fminf(fmaxf(ao, 1e-4f), 1.0f - 1e-4f);
                if (isnan(ao)) ao = 0.5f;
                aout_s[c2] = ao;
            }
            float mu = m;
            if (isnan(mu)) mu = 0.f;
            mu = fminf(fmaxf(mu, -10000.f), 10000.f);
            out[(size_t)n * 512 + tid] = mu;
            out[69632 + (size_t)n * 544 + tid] = mu;
            __syncthreads();
            if (tid < 32) {
                float ao = aout_s[tid];
                out[65536 + n * 32 + tid] = ao;
                out[69632 + n * 544 + 512 + tid] = ao;
            }
        }
    }
}

extern "C" void kernel_launch(void* const* d_in, const int* in_sizes, int n_in,
                              void* d_out, int out_size, void* d_ws, size_t ws_size,
                              hipStream_t stream) {
    const float* x  = (const float*)d_in[0];
    const float* w  = (const float*)d_in[1];
    const float* bu = (const float*)d_in[2];
    const float* ba = (const float*)d_in[3];
    float* out = (float*)d_out;
    __hip_bfloat16* v  = (__hip_bfloat16*)d_ws;               // 37.7 MB
    float* gpart       = (float*)((char*)d_ws + (40u << 20)); // [3][128][6][1088] ~9.6MB
    float* gfct        = (float*)((char*)d_ws + (52u << 20)); // [128][288] 147KB
    unsigned int* cnt  = (unsigned int*)((char*)d_ws + (53u << 20)); // [128]
    const unsigned short* vv = (const unsigned short*)v;

    conv_v_kernel<<<dim3(576), dim3(256), 0, stream>>>(x, w, v, cnt);
    em_sweep_kernel<<<dim3(768), dim3(512), 0, stream>>>(
        x, vv, bu, ba, gpart, gfct, cnt, out, 0);
    em_sweep_kernel<<<dim3(768), dim3(512), 0, stream>>>(
        x, vv, bu, ba, gpart, gfct, cnt, out, 1);
    em_sweep_kernel<<<dim3(768), dim3(512), 0, stream>>>(
        x, vv, bu, ba, gpart, gfct, cnt, out, 2);
}

// Round 15
// 113.687 us; speedup vs baseline: 2.1714x; 2.1714x over previous
//
#include <hip/hip_runtime.h>
#include <hip/hip_bf16.h>
#include <math.h>

#define EPSV 1e-6f
#define LAMBDAV 1e-3f
#define LN_2PI 1.8378770664093453f

__device__ __forceinline__ float bflo(unsigned int u) {
    union { unsigned int i; float f; } x; x.i = u << 16; return x.f;
}
__device__ __forceinline__ float bfhi(unsigned int u) {
    union { unsigned int i; float f; } x; x.i = u & 0xffff0000u; return x.f;
}
__device__ __forceinline__ unsigned short f2bf(float f) {
    __hip_bfloat16 h = __float2bfloat16(f);
    return *(unsigned short*)&h;
}

typedef __attribute__((ext_vector_type(8))) short s8v;
typedef __attribute__((ext_vector_type(4))) float f4v;
typedef __attribute__((ext_vector_type(2))) int i2v;

// DPP lane-permute move (VALU-latency cross-lane, no LDS pipe).
template<int CTRL>
__device__ __forceinline__ float dpp_mv(float x) {
    return __int_as_float(__builtin_amdgcn_update_dpp(
        0, __float_as_int(x), CTRL, 0xF, 0xF, true));
}
__device__ __forceinline__ float x16_sum(float x) {
#if __has_builtin(__builtin_amdgcn_permlane16_swap)
    i2v r = __builtin_amdgcn_permlane16_swap(__float_as_int(x), __float_as_int(x), false, false);
    return __int_as_float(r.x) + __int_as_float(r.y);
#else
    return x + __int_as_float(__builtin_amdgcn_ds_swizzle(__float_as_int(x), 0x401F));
#endif
}
__device__ __forceinline__ float x16_max(float x) {
#if __has_builtin(__builtin_amdgcn_permlane16_swap)
    i2v r = __builtin_amdgcn_permlane16_swap(__float_as_int(x), __float_as_int(x), false, false);
    return fmaxf(__int_as_float(r.x), __int_as_float(r.y));
#else
    return fmaxf(x, __int_as_float(__builtin_amdgcn_ds_swizzle(__float_as_int(x), 0x401F)));
#endif
}
__device__ __forceinline__ float xhalf_sum(float x) {
#if __has_builtin(__builtin_amdgcn_permlane32_swap)
    i2v r = __builtin_amdgcn_permlane32_swap(__float_as_int(x), __float_as_int(x), false, false);
    return __int_as_float(r.x) + __int_as_float(r.y);
#else
    return x + __shfl_xor(x, 32, 64);
#endif
}
__device__ __forceinline__ float red_max32(float x) {
    x = fmaxf(x, dpp_mv<0xB1>(x));    // quad_perm [1,0,3,2]  (xor 1)
    x = fmaxf(x, dpp_mv<0x4E>(x));    // quad_perm [2,3,0,1]  (xor 2)
    x = fmaxf(x, dpp_mv<0x124>(x));   // row_ror:4
    x = fmaxf(x, dpp_mv<0x128>(x));   // row_ror:8
    return x16_max(x);
}
__device__ __forceinline__ float red_sum32(float x) {
    x += dpp_mv<0xB1>(x);
    x += dpp_mv<0x4E>(x);
    x += dpp_mv<0x124>(x);
    x += dpp_mv<0x128>(x);
    return x16_sum(x);
}
__device__ __forceinline__ float red_sum16(float x) {
    x += dpp_mv<0xB1>(x);
    x += dpp_mv<0x4E>(x);
    x += dpp_mv<0x124>(x);
    x += dpp_mv<0x128>(x);
    return x;
}

// Kernel 1: MFMA conv, M-split: 576 blocks = (i2, cq-half), ~5 blocks/CU.
// LDS-transposed epilogue (R12, verified). w stage vectorized to float4 (R14,
// verified-correct). No fences/atomics anywhere (R14 lesson: per-block
// device-scope fences serialize ~0.2us of L2 maintenance each).
__global__ __launch_bounds__(256)
void conv_v_kernel(const float* __restrict__ x, const float* __restrict__ w,
                   __hip_bfloat16* __restrict__ vout)
{
    __shared__ unsigned short wb[256 * 40];  // [cq_local][p pad40]
    __shared__ unsigned short pb[128 * 40];  // [n][p pad40]
    __shared__ unsigned short st[16 * 264];  // [n_local][cq_local pad264]

    const int bid = blockIdx.x;
    const int i2  = bid >> 1;
    const int mh  = bid & 1;                 // cq half: [mh*256, mh*256+256)
    const int tid = threadIdx.x;

    // zero k=16..31 padding (mfma reads k<32)
    for (int u = tid; u < 256 * 8; u += 256) {
        int r = u >> 3, j = u & 7;
        *(unsigned int*)&wb[r * 40 + 16 + j * 2] = 0;
    }
    for (int u = tid; u < 128 * 8; u += 256) {
        int r = u >> 3, j = u & 7;
        *(unsigned int*)&pb[r * 40 + 16 + j * 2] = 0;
    }
    // stage w fp32 -> wb bf16, vectorized: 4x float4 per thread
    {
        const float* wsrc = w + (size_t)i2 * 8192 + mh * 4096;
        #pragma unroll
        for (int uu = 0; uu < 4; ++uu) {
            int idx = (uu * 256 + tid) * 4;        // cl*256 + p*16 + q, q%4==0
            float4 f = *(const float4*)&wsrc[idx];
            int cl = idx >> 8, p = (idx >> 4) & 15, q = idx & 15;
            wb[(cl * 16 + q + 0) * 40 + p] = f2bf(f.x);
            wb[(cl * 16 + q + 1) * 40 + p] = f2bf(f.y);
            wb[(cl * 16 + q + 2) * 40 + p] = f2bf(f.z);
            wb[(cl * 16 + q + 3) * 40 + p] = f2bf(f.w);
        }
    }
    // fused gather: pb[nn][p] from x via reference reshape scramble
    #pragma unroll
    for (int u = 0; u < 8; ++u) {
        int idx = u * 256 + tid;               // nn*16 + p
        int nn = idx >> 4, p = idx & 15;
        int e  = i2 * 16 + p;
        int k2 = e >> 9, c2 = e & 511;
        int f  = k2 * 544 + c2;
        int ci = f / 9, kk = f - ci * 9;
        int bi = nn >> 6, oi = (nn >> 3) & 7, oj = nn & 7;
        int row = 2 * oi + kk / 3 - 1;
        int col = 2 * oj + (kk - (kk / 3) * 3) - 1;
        float val = 0.f;
        if ((unsigned)row < 16u && (unsigned)col < 16u)
            val = x[((bi * 16 + row) * 16 + col) * 544 + ci];
        pb[nn * 40 + p] = f2bf(val);
    }
    __syncthreads();

    const int lane = tid & 63;
    const int wv   = tid >> 6;
    const int l16  = lane & 15;
    const int quad = lane >> 4;
    const int cq0l = wv * 64;                  // local cq base of this wave

    s8v afrag[4], bfrag[8];
    #pragma unroll
    for (int mt = 0; mt < 4; ++mt)
        afrag[mt] = *(const s8v*)&wb[(cq0l + mt * 16 + l16) * 40 + quad * 8];
    #pragma unroll
    for (int nt = 0; nt < 8; ++nt)
        bfrag[nt] = *(const s8v*)&pb[(nt * 16 + l16) * 40 + quad * 8];

    const int srow = tid >> 4;                 // readout row 0..15
    const int schk = tid & 15;                 // readout 16-short chunk
    #pragma unroll
    for (int nt = 0; nt < 8; ++nt) {
        #pragma unroll
        for (int mt = 0; mt < 4; ++mt) {
            f4v acc = {0.f, 0.f, 0.f, 0.f};
            acc = __builtin_amdgcn_mfma_f32_16x16x32_bf16(afrag[mt], bfrag[nt], acc, 0, 0, 0);
            int ccol = cq0l + mt * 16 + quad * 4;   // 0..255 within mh half
            unsigned int lo = f2bf(acc[0]) | ((unsigned int)f2bf(acc[1]) << 16);
            unsigned int hi = f2bf(acc[2]) | ((unsigned int)f2bf(acc[3]) << 16);
            uint2 pk; pk.x = lo; pk.y = hi;
            *(uint2*)&st[l16 * 264 + ccol] = pk;    // row n=l16, 8B aligned
        }
        __syncthreads();
        // coalesced writeback: 16 threads/row x 32 B each = 512 B run
        {
            uint4 d0 = *(const uint4*)&st[srow * 264 + schk * 16];
            uint4 d1 = *(const uint4*)&st[srow * 264 + schk * 16 + 8];
            int nl = nt * 16 + srow;
            unsigned short* dst = (unsigned short*)vout
                + ((size_t)nl * 288 + i2) * 512 + mh * 256 + schk * 16;
            *(uint4*)dst = d0;
            *(uint4*)(dst + 8) = d1;
        }
        __syncthreads();
    }
}

// Kernel 2: one EM sweep (iteration t), grid 768 = (n, h in 0..5), 512 thr.
// t=0 computes fct from x and caches it in gfct; t>0 loads it coalesced.
// Partials to this block's own gpart slot with plain stores; visibility via
// stream kernel boundaries ONLY (R14: per-block fences serialize; R3:
// acquire spins thrash L2; R13: coop launch crashes the harness).
__global__ __launch_bounds__(512)
void em_sweep_kernel(const float* __restrict__ x,
                     const unsigned short* __restrict__ v,   // [n][i][cq] bf16
                     const float* __restrict__ beta_u,
                     const float* __restrict__ beta_a,
                     float* __restrict__ gpart,              // [t][n][6][1088]
                     float* __restrict__ gfct,               // [n][288]
                     const int t)
{
    __shared__ float fct_s[288];            // a/(a+eps)
    __shared__ float red_s[8 * 64 * 17];    // [wave][lane][s0|s1[8]|s2[8]]
    __shared__ float mu_s[32 * 17];
    __shared__ float i2ss_s[32 * 17];
    __shared__ float kc_s[32];

    const int bid = blockIdx.x;
    const int n   = bid & 127;
    const int h   = bid >> 7;               // 0..5, rows [h*48, h*48+48)
    const int tid = threadIdx.x;
    const int bi = n >> 6, oi = (n >> 3) & 7, oj = n & 7;

    if (t == 0) {
        if (tid < 288) {
            int k2 = tid >> 5;
            int c2 = 512 + (tid & 31);
            int f  = k2 * 544 + c2;
            int ci = f / 9;
            int kk = f - ci * 9;
            int row = 2 * oi + kk / 3 - 1;
            int col = 2 * oj + (kk - (kk / 3) * 3) - 1;
            float a = 0.f;
            if ((unsigned)row < 16u && (unsigned)col < 16u)
                a = x[((bi * 16 + row) * 16 + col) * 544 + ci];
            float fc = a / (a + EPSV);   // sum_c r*a == a -> rr = softmax * fct
            fct_s[tid] = fc;
            if (h == 0) gfct[n * 288 + tid] = fc;   // cache for t=1,2
        }
    } else {
        if (tid < 288) fct_s[tid] = gfct[n * 288 + tid];
    }

    // finalize previous iteration's stats from all 6 slices (t>0)
    if (t > 0) {
        const int c2 = tid >> 4, q2 = tid & 15;
        const float* pa = gpart + ((size_t)(t - 1) * 128 + n) * 6 * 1088;
        float S1 = 0.f, S2 = 0.f, S0 = 0.f;
        #pragma unroll
        for (int j = 0; j < 6; ++j) {
            S1 += pa[j * 1088 + tid];
            S2 += pa[j * 1088 + 512 + tid];
            S0 += pa[j * 1088 + 1024 + c2];
        }
        float invr = 1.0f / (S0 + EPSV);
        float w0  = S0 * invr;
        float m   = S1 * invr;
        float s2p = S2 * invr;
        float sig = s2p - m * m * (2.0f - w0);   // == sum coeff*(v-mu)^2
        sig = fmaxf(sig + EPSV, 1e-4f);
        float hl = 0.5f * logf(sig);
        mu_s[c2 * 17 + q2]   = m;
        i2ss_s[c2 * 17 + q2] = 1.0f / (2.0f * sig);
        float shl = red_sum16(hl);
        if (q2 == 0) {
            float bu  = beta_u[c2];
            float cs  = (16.0f * bu + shl) * S0;
            float arg = LAMBDAV * (beta_a[c2] - cs);
            float ao  = 1.0f / (1.0f + expf(-arg));
            ao = fminf(fmaxf(ao, 1e-4f), 1.0f - 1e-4f);
            kc_s[c2]  = logf(ao + EPSV) - shl - 8.0f * LN_2PI;
        }
    }
    __syncthreads();

    const unsigned short* vb = v + (size_t)n * 288 * 512;
    const int wv   = tid >> 6;      // wave 0..7
    const int lane = tid & 63;
    const int c    = lane & 31;
    const int qh   = lane >> 5;     // q-half 0/1
    const int qb   = qh * 8;
    const unsigned short* base = vb + c * 16 + qb;

    float mu8[8], is8[8], kcv = 0.f;
    if (t > 0) {
        #pragma unroll
        for (int j = 0; j < 8; ++j) {
            mu8[j] = mu_s[c * 17 + qb + j];
            is8[j] = i2ss_s[c * 17 + qb + j];
        }
        kcv = kc_s[c];
    }

    float s0 = 0.f, s1[8], s2[8];
    #pragma unroll
    for (int j = 0; j < 8; ++j) { s1[j] = 0.f; s2[j] = 0.f; }

    const int kofs = h * 48;         // rows kofs + kp*16 + {wv, wv+8}, kp<3

    // prefetch pair 0
    uint4 ua = *(const uint4*)(base + (size_t)(kofs + 0 + wv) * 512);
    uint4 ub = *(const uint4*)(base + (size_t)(kofs + 8 + wv) * 512);

    #pragma unroll
    for (int kp = 0; kp < 3; ++kp) {
        const int ia = kofs + kp * 16 + wv;
        const int ib = ia + 8;
        uint4 una = ua, unb = ub;
        if (kp < 2) {   // issue next pair before the compute chain
            una = *(const uint4*)(base + (size_t)(ia + 16) * 512);
            unb = *(const uint4*)(base + (size_t)(ia + 24) * 512);
        }
        float va[8], vvb[8];
        va[0] = bflo(ua.x); va[1] = bfhi(ua.x);
        va[2] = bflo(ua.y); va[3] = bfhi(ua.y);
        va[4] = bflo(ua.z); va[5] = bfhi(ua.z);
        va[6] = bflo(ua.w); va[7] = bfhi(ua.w);
        vvb[0] = bflo(ub.x); vvb[1] = bfhi(ub.x);
        vvb[2] = bflo(ub.y); vvb[3] = bfhi(ub.y);
        vvb[4] = bflo(ub.z); vvb[5] = bfhi(ub.z);
        vvb[6] = bflo(ub.w); vvb[7] = bfhi(ub.w);

        float rra, rrb;
        if (t == 0) {
            rra = fct_s[ia] * 0.03125f;
            rrb = fct_s[ib] * 0.03125f;
        } else {
            float pa = 0.f, pb2 = 0.f;
            #pragma unroll
            for (int j = 0; j < 8; ++j) {
                float da = va[j] - mu8[j];
                float db = vvb[j] - mu8[j];
                pa  += da * da * is8[j];
                pb2 += db * db * is8[j];
            }
            pa  = xhalf_sum(pa);      // combine q-halves (xor32, VALU)
            pb2 = xhalf_sum(pb2);
            float acca = kcv - pa;
            float accb = kcv - pb2;
            float mxa = red_max32(acca);
            float mxb = red_max32(accb);
            float ea = __expf(acca - mxa);
            float eb = __expf(accb - mxb);
            float sa = red_sum32(ea);
            float sb = red_sum32(eb);
            rra = (ea / sa) * fct_s[ia];
            rrb = (eb / sb) * fct_s[ib];
        }

        s0 += rra + rrb;
        #pragma unroll
        for (int j = 0; j < 8; ++j) {
            s1[j] += rra * va[j] + rrb * vvb[j];
            s2[j] += rra * va[j] * va[j] + rrb * vvb[j] * vvb[j];
        }
        ua = una; ub = unb;
    }

    // per-wave partials -> LDS (stride 17: 2-way bank alias = free)
    {
        float* dst = &red_s[(wv * 64 + lane) * 17];
        dst[0] = s0;
        #pragma unroll
        for (int j = 0; j < 8; ++j) { dst[1 + j] = s1[j]; dst[9 + j] = s2[j]; }
    }
    __syncthreads();

    // final 8-way reduce -> this block's own gpart slot (plain stores)
    {
        const int c2 = tid >> 4, q2 = tid & 15;
        const int qh2 = q2 >> 3, j2 = q2 & 7;
        float S0 = 0.f, S1 = 0.f, S2 = 0.f;
        #pragma unroll
        for (int wvi = 0; wvi < 8; ++wvi) {
            S0 += red_s[(wvi * 64 + c2) * 17];
            const float* sp = &red_s[(wvi * 64 + qh2 * 32 + c2) * 17];
            S1 += sp[1 + j2];
            S2 += sp[9 + j2];
        }
        float* po = gpart + (((size_t)t * 128 + n) * 6 + h) * 1088;
        po[tid] = S1;
        po[512 + tid] = S2;
        if (q2 == 0) po[1024 + c2] = S0;
    }
}

// Kernel 3: epilogue — finalize t=2 stats, write p_out / a_out / out.
__global__ __launch_bounds__(512)
void em_final_kernel(const float* __restrict__ gpart,
                     const float* __restrict__ beta_u,
                     const float* __restrict__ beta_a,
                     float* __restrict__ out)
{
    __shared__ float aout_s[32];
    const int n   = blockIdx.x;
    const int tid = threadIdx.x;           // 512
    const int c2 = tid >> 4, q2 = tid & 15;

    const float* pa = gpart + ((size_t)2 * 128 + n) * 6 * 1088;
    float S1 = 0.f, S2 = 0.f, S0 = 0.f;
    #pragma unroll
    for (int j = 0; j < 6; ++j) {
        S1 += pa[j * 1088 + tid];
        S2 += pa[j * 1088 + 512 + tid];
        S0 += pa[j * 1088 + 1024 + c2];
    }
    float invr = 1.0f / (S0 + EPSV);
    float w0  = S0 * invr;
    float m   = S1 * invr;
    float s2p = S2 * invr;
    float sig = s2p - m * m * (2.0f - w0);
    sig = fmaxf(sig + EPSV, 1e-4f);
    float hl = 0.5f * logf(sig);
    float shl = red_sum16(hl);
    if (q2 == 0) {
        float bu  = beta_u[c2];
        float cs  = (16.0f * bu + shl) * S0;
        float arg = LAMBDAV * (beta_a[c2] - cs);
        float ao  = 1.0f / (1.0f + expf(-arg));
        ao = fminf(fmaxf(ao, 1e-4f), 1.0f - 1e-4f);
        if (isnan(ao)) ao = 0.5f;
        aout_s[c2] = ao;
    }
    float mu = m;
    if (isnan(mu)) mu = 0.f;
    mu = fminf(fmaxf(mu, -10000.f), 10000.f);
    out[(size_t)n * 512 + tid] = mu;
    out[69632 + (size_t)n * 544 + tid] = mu;
    __syncthreads();
    if (tid < 32) {
        float ao = aout_s[tid];
        out[65536 + n * 32 + tid] = ao;
        out[69632 + n * 544 + 512 + tid] = ao;
    }
}

extern "C" void kernel_launch(void* const* d_in, const int* in_sizes, int n_in,
                              void* d_out, int out_size, void* d_ws, size_t ws_size,
                              hipStream_t stream) {
    const float* x  = (const float*)d_in[0];
    const float* w  = (const float*)d_in[1];
    const float* bu = (const float*)d_in[2];
    const float* ba = (const float*)d_in[3];
    float* out = (float*)d_out;
    __hip_bfloat16* v = (__hip_bfloat16*)d_ws;               // 37.7 MB
    float* gpart = (float*)((char*)d_ws + (40u << 20));      // [3][128][6][1088]
    float* gfct  = (float*)((char*)d_ws + (52u << 20));      // [128][288]
    const unsigned short* vv = (const unsigned short*)v;

    conv_v_kernel<<<dim3(576), dim3(256), 0, stream>>>(x, w, v);
    em_sweep_kernel<<<dim3(768), dim3(512), 0, stream>>>(x, vv, bu, ba, gpart, gfct, 0);
    em_sweep_kernel<<<dim3(768), dim3(512), 0, stream>>>(x, vv, bu, ba, gpart, gfct, 1);
    em_sweep_kernel<<<dim3(768), dim3(512), 0, stream>>>(x, vv, bu, ba, gpart, gfct, 2);
    em_final_kernel<<<dim3(128), dim3(512), 0, stream>>>(gpart, bu, ba, out);
}

// Round 16
// 111.693 us; speedup vs baseline: 2.2101x; 1.0179x over previous
//
#include <hip/hip_runtime.h>
#include <hip/hip_bf16.h>
#include <math.h>

#define EPSV 1e-6f
#define LAMBDAV 1e-3f
#define LN_2PI 1.8378770664093453f

__device__ __forceinline__ float bflo(unsigned int u) {
    union { unsigned int i; float f; } x; x.i = u << 16; return x.f;
}
__device__ __forceinline__ float bfhi(unsigned int u) {
    union { unsigned int i; float f; } x; x.i = u & 0xffff0000u; return x.f;
}
__device__ __forceinline__ unsigned short f2bf(float f) {
    __hip_bfloat16 h = __float2bfloat16(f);
    return *(unsigned short*)&h;
}

typedef __attribute__((ext_vector_type(8))) short s8v;
typedef __attribute__((ext_vector_type(4))) float f4v;
typedef __attribute__((ext_vector_type(2))) int i2v;

// DPP lane-permute move (VALU-latency cross-lane, no LDS pipe).
template<int CTRL>
__device__ __forceinline__ float dpp_mv(float x) {
    return __int_as_float(__builtin_amdgcn_update_dpp(
        0, __float_as_int(x), CTRL, 0xF, 0xF, true));
}
__device__ __forceinline__ float x16_sum(float x) {
#if __has_builtin(__builtin_amdgcn_permlane16_swap)
    i2v r = __builtin_amdgcn_permlane16_swap(__float_as_int(x), __float_as_int(x), false, false);
    return __int_as_float(r.x) + __int_as_float(r.y);
#else
    return x + __int_as_float(__builtin_amdgcn_ds_swizzle(__float_as_int(x), 0x401F));
#endif
}
__device__ __forceinline__ float x16_max(float x) {
#if __has_builtin(__builtin_amdgcn_permlane16_swap)
    i2v r = __builtin_amdgcn_permlane16_swap(__float_as_int(x), __float_as_int(x), false, false);
    return fmaxf(__int_as_float(r.x), __int_as_float(r.y));
#else
    return fmaxf(x, __int_as_float(__builtin_amdgcn_ds_swizzle(__float_as_int(x), 0x401F)));
#endif
}
__device__ __forceinline__ float xhalf_sum(float x) {
#if __has_builtin(__builtin_amdgcn_permlane32_swap)
    i2v r = __builtin_amdgcn_permlane32_swap(__float_as_int(x), __float_as_int(x), false, false);
    return __int_as_float(r.x) + __int_as_float(r.y);
#else
    return x + __shfl_xor(x, 32, 64);
#endif
}
__device__ __forceinline__ float red_max32(float x) {
    x = fmaxf(x, dpp_mv<0xB1>(x));    // quad_perm [1,0,3,2]  (xor 1)
    x = fmaxf(x, dpp_mv<0x4E>(x));    // quad_perm [2,3,0,1]  (xor 2)
    x = fmaxf(x, dpp_mv<0x124>(x));   // row_ror:4
    x = fmaxf(x, dpp_mv<0x128>(x));   // row_ror:8
    return x16_max(x);
}
__device__ __forceinline__ float red_sum32(float x) {
    x += dpp_mv<0xB1>(x);
    x += dpp_mv<0x4E>(x);
    x += dpp_mv<0x124>(x);
    x += dpp_mv<0x128>(x);
    return x16_sum(x);
}
__device__ __forceinline__ float red_sum16(float x) {
    x += dpp_mv<0xB1>(x);
    x += dpp_mv<0x4E>(x);
    x += dpp_mv<0x124>(x);
    x += dpp_mv<0x128>(x);
    return x;
}

// Kernel 1: MFMA conv, M-split: 576 blocks = (i2, cq-half), 4 blocks/CU.
// Epilogue is WAVE-PRIVATE LDS-transpose: each wave stages its own 16n x
// 64cq band into its own sub-buffer and reads it back itself -> zero
// barriers after the initial staging sync. (R12's shared-tile epilogue had
// 16 __syncthreads; each emits s_waitcnt vmcnt(0) first, fully draining the
// global stores every nt iteration ~ 16 exposed store latencies/block.)
__global__ __launch_bounds__(256)
void conv_v_kernel(const float* __restrict__ x, const float* __restrict__ w,
                   __hip_bfloat16* __restrict__ vout)
{
    __shared__ unsigned short wb[256 * 40];  // [cq_local][p pad40]
    __shared__ unsigned short pb[128 * 40];  // [n][p pad40]
    __shared__ unsigned short st[4][16][68]; // per-wave [n][cq_local pad68]

    const int bid = blockIdx.x;
    const int i2  = bid >> 1;
    const int mh  = bid & 1;                 // cq half: [mh*256, mh*256+256)
    const int tid = threadIdx.x;

    // zero k=16..31 padding (mfma reads k<32)
    for (int u = tid; u < 256 * 8; u += 256) {
        int r = u >> 3, j = u & 7;
        *(unsigned int*)&wb[r * 40 + 16 + j * 2] = 0;
    }
    for (int u = tid; u < 128 * 8; u += 256) {
        int r = u >> 3, j = u & 7;
        *(unsigned int*)&pb[r * 40 + 16 + j * 2] = 0;
    }
    // stage w fp32 -> wb bf16, vectorized: 4x float4 per thread
    {
        const float* wsrc = w + (size_t)i2 * 8192 + mh * 4096;
        #pragma unroll
        for (int uu = 0; uu < 4; ++uu) {
            int idx = (uu * 256 + tid) * 4;        // cl*256 + p*16 + q, q%4==0
            float4 f = *(const float4*)&wsrc[idx];
            int cl = idx >> 8, p = (idx >> 4) & 15, q = idx & 15;
            wb[(cl * 16 + q + 0) * 40 + p] = f2bf(f.x);
            wb[(cl * 16 + q + 1) * 40 + p] = f2bf(f.y);
            wb[(cl * 16 + q + 2) * 40 + p] = f2bf(f.z);
            wb[(cl * 16 + q + 3) * 40 + p] = f2bf(f.w);
        }
    }
    // fused gather: pb[nn][p] from x via reference reshape scramble
    #pragma unroll
    for (int u = 0; u < 8; ++u) {
        int idx = u * 256 + tid;               // nn*16 + p
        int nn = idx >> 4, p = idx & 15;
        int e  = i2 * 16 + p;
        int k2 = e >> 9, c2 = e & 511;
        int f  = k2 * 544 + c2;
        int ci = f / 9, kk = f - ci * 9;
        int bi = nn >> 6, oi = (nn >> 3) & 7, oj = nn & 7;
        int row = 2 * oi + kk / 3 - 1;
        int col = 2 * oj + (kk - (kk / 3) * 3) - 1;
        float val = 0.f;
        if ((unsigned)row < 16u && (unsigned)col < 16u)
            val = x[((bi * 16 + row) * 16 + col) * 544 + ci];
        pb[nn * 40 + p] = f2bf(val);
    }
    __syncthreads();   // the only barrier: wb/pb staged by all threads

    const int lane = tid & 63;
    const int wv   = tid >> 6;
    const int l16  = lane & 15;
    const int quad = lane >> 4;
    const int cq0l = wv * 64;                  // local cq base of this wave

    s8v afrag[4], bfrag[8];
    #pragma unroll
    for (int mt = 0; mt < 4; ++mt)
        afrag[mt] = *(const s8v*)&wb[(cq0l + mt * 16 + l16) * 40 + quad * 8];
    #pragma unroll
    for (int nt = 0; nt < 8; ++nt)
        bfrag[nt] = *(const s8v*)&pb[(nt * 16 + l16) * 40 + quad * 8];

    const int rrow = lane >> 2;                // readback n-row 0..15
    const int rchk = lane & 3;                 // 16-short chunk in 64-cq band
    #pragma unroll
    for (int nt = 0; nt < 8; ++nt) {
        #pragma unroll
        for (int mt = 0; mt < 4; ++mt) {
            f4v acc = {0.f, 0.f, 0.f, 0.f};
            acc = __builtin_amdgcn_mfma_f32_16x16x32_bf16(afrag[mt], bfrag[nt], acc, 0, 0, 0);
            int cl = mt * 16 + quad * 4;            // 0..63 within wave band
            unsigned int lo = f2bf(acc[0]) | ((unsigned int)f2bf(acc[1]) << 16);
            unsigned int hi = f2bf(acc[2]) | ((unsigned int)f2bf(acc[3]) << 16);
            uint2 pk; pk.x = lo; pk.y = hi;
            *(uint2*)&st[wv][l16][cl] = pk;         // wave-private, 8B aligned
        }
        // same-wave readback: compiler-inserted lgkmcnt orders ds ops;
        // no barrier -> global stores overlap next nt's MFMAs.
        {
            uint4 d0 = *(const uint4*)&st[wv][rrow][rchk * 16];
            uint4 d1 = *(const uint4*)&st[wv][rrow][rchk * 16 + 8];
            int nl = nt * 16 + rrow;
            unsigned short* dst = (unsigned short*)vout
                + ((size_t)nl * 288 + i2) * 512 + mh * 256 + wv * 64 + rchk * 16;
            *(uint4*)dst = d0;
            *(uint4*)(dst + 8) = d1;
        }
    }
}

// Kernel 2: one EM sweep (iteration t), grid 768 = (n, h in 0..5), 512 thr.
// t=0 computes fct from x and caches it in gfct; t>0 loads it coalesced.
// Partials to this block's own gpart slot with plain stores; visibility via
// stream kernel boundaries ONLY (R14: per-block fences serialize; R3:
// acquire spins thrash L2; R13: coop launch crashes the harness).
__global__ __launch_bounds__(512)
void em_sweep_kernel(const float* __restrict__ x,
                     const unsigned short* __restrict__ v,   // [n][i][cq] bf16
                     const float* __restrict__ beta_u,
                     const float* __restrict__ beta_a,
                     float* __restrict__ gpart,              // [t][n][6][1088]
                     float* __restrict__ gfct,               // [n][288]
                     const int t)
{
    __shared__ float fct_s[288];            // a/(a+eps)
    __shared__ float red_s[8 * 64 * 17];    // [wave][lane][s0|s1[8]|s2[8]]
    __shared__ float mu_s[32 * 17];
    __shared__ float i2ss_s[32 * 17];
    __shared__ float kc_s[32];

    const int bid = blockIdx.x;
    const int n   = bid & 127;
    const int h   = bid >> 7;               // 0..5, rows [h*48, h*48+48)
    const int tid = threadIdx.x;
    const int bi = n >> 6, oi = (n >> 3) & 7, oj = n & 7;

    if (t == 0) {
        if (tid < 288) {
            int k2 = tid >> 5;
            int c2 = 512 + (tid & 31);
            int f  = k2 * 544 + c2;
            int ci = f / 9;
            int kk = f - ci * 9;
            int row = 2 * oi + kk / 3 - 1;
            int col = 2 * oj + (kk - (kk / 3) * 3) - 1;
            float a = 0.f;
            if ((unsigned)row < 16u && (unsigned)col < 16u)
                a = x[((bi * 16 + row) * 16 + col) * 544 + ci];
            float fc = a / (a + EPSV);   // sum_c r*a == a -> rr = softmax * fct
            fct_s[tid] = fc;
            if (h == 0) gfct[n * 288 + tid] = fc;   // cache for t=1,2
        }
    } else {
        if (tid < 288) fct_s[tid] = gfct[n * 288 + tid];
    }

    // finalize previous iteration's stats from all 6 slices (t>0)
    if (t > 0) {
        const int c2 = tid >> 4, q2 = tid & 15;
        const float* pa = gpart + ((size_t)(t - 1) * 128 + n) * 6 * 1088;
        float S1 = 0.f, S2 = 0.f, S0 = 0.f;
        #pragma unroll
        for (int j = 0; j < 6; ++j) {
            S1 += pa[j * 1088 + tid];
            S2 += pa[j * 1088 + 512 + tid];
            S0 += pa[j * 1088 + 1024 + c2];
        }
        float invr = 1.0f / (S0 + EPSV);
        float w0  = S0 * invr;
        float m   = S1 * invr;
        float s2p = S2 * invr;
        float sig = s2p - m * m * (2.0f - w0);   // == sum coeff*(v-mu)^2
        sig = fmaxf(sig + EPSV, 1e-4f);
        float hl = 0.5f * logf(sig);
        mu_s[c2 * 17 + q2]   = m;
        i2ss_s[c2 * 17 + q2] = 1.0f / (2.0f * sig);
        float shl = red_sum16(hl);
        if (q2 == 0) {
            float bu  = beta_u[c2];
            float cs  = (16.0f * bu + shl) * S0;
            float arg = LAMBDAV * (beta_a[c2] - cs);
            float ao  = 1.0f / (1.0f + expf(-arg));
            ao = fminf(fmaxf(ao, 1e-4f), 1.0f - 1e-4f);
            kc_s[c2]  = logf(ao + EPSV) - shl - 8.0f * LN_2PI;
        }
    }
    __syncthreads();

    const unsigned short* vb = v + (size_t)n * 288 * 512;
    const int wv   = tid >> 6;      // wave 0..7
    const int lane = tid & 63;
    const int c    = lane & 31;
    const int qh   = lane >> 5;     // q-half 0/1
    const int qb   = qh * 8;
    const unsigned short* base = vb + c * 16 + qb;

    float mu8[8], is8[8], kcv = 0.f;
    if (t > 0) {
        #pragma unroll
        for (int j = 0; j < 8; ++j) {
            mu8[j] = mu_s[c * 17 + qb + j];
            is8[j] = i2ss_s[c * 17 + qb + j];
        }
        kcv = kc_s[c];
    }

    float s0 = 0.f, s1[8], s2[8];
    #pragma unroll
    for (int j = 0; j < 8; ++j) { s1[j] = 0.f; s2[j] = 0.f; }

    const int kofs = h * 48;         // rows kofs + kp*16 + {wv, wv+8}, kp<3

    // prefetch pair 0
    uint4 ua = *(const uint4*)(base + (size_t)(kofs + 0 + wv) * 512);
    uint4 ub = *(const uint4*)(base + (size_t)(kofs + 8 + wv) * 512);

    #pragma unroll
    for (int kp = 0; kp < 3; ++kp) {
        const int ia = kofs + kp * 16 + wv;
        const int ib = ia + 8;
        uint4 una = ua, unb = ub;
        if (kp < 2) {   // issue next pair before the compute chain
            una = *(const uint4*)(base + (size_t)(ia + 16) * 512);
            unb = *(const uint4*)(base + (size_t)(ia + 24) * 512);
        }
        float va[8], vvb[8];
        va[0] = bflo(ua.x); va[1] = bfhi(ua.x);
        va[2] = bflo(ua.y); va[3] = bfhi(ua.y);
        va[4] = bflo(ua.z); va[5] = bfhi(ua.z);
        va[6] = bflo(ua.w); va[7] = bfhi(ua.w);
        vvb[0] = bflo(ub.x); vvb[1] = bfhi(ub.x);
        vvb[2] = bflo(ub.y); vvb[3] = bfhi(ub.y);
        vvb[4] = bflo(ub.z); vvb[5] = bfhi(ub.z);
        vvb[6] = bflo(ub.w); vvb[7] = bfhi(ub.w);

        float rra, rrb;
        if (t == 0) {
            rra = fct_s[ia] * 0.03125f;
            rrb = fct_s[ib] * 0.03125f;
        } else {
            float pa = 0.f, pb2 = 0.f;
            #pragma unroll
            for (int j = 0; j < 8; ++j) {
                float da = va[j] - mu8[j];
                float db = vvb[j] - mu8[j];
                pa  += da * da * is8[j];
                pb2 += db * db * is8[j];
            }
            pa  = xhalf_sum(pa);      // combine q-halves (xor32, VALU)
            pb2 = xhalf_sum(pb2);
            float acca = kcv - pa;
            float accb = kcv - pb2;
            float mxa = red_max32(acca);
            float mxb = red_max32(accb);
            float ea = __expf(acca - mxa);
            float eb = __expf(accb - mxb);
            float sa = red_sum32(ea);
            float sb = red_sum32(eb);
            rra = (ea / sa) * fct_s[ia];
            rrb = (eb / sb) * fct_s[ib];
        }

        s0 += rra + rrb;
        #pragma unroll
        for (int j = 0; j < 8; ++j) {
            s1[j] += rra * va[j] + rrb * vvb[j];
            s2[j] += rra * va[j] * va[j] + rrb * vvb[j] * vvb[j];
        }
        ua = una; ub = unb;
    }

    // per-wave partials -> LDS (stride 17: 2-way bank alias = free)
    {
        float* dst = &red_s[(wv * 64 + lane) * 17];
        dst[0] = s0;
        #pragma unroll
        for (int j = 0; j < 8; ++j) { dst[1 + j] = s1[j]; dst[9 + j] = s2[j]; }
    }
    __syncthreads();

    // final 8-way reduce -> this block's own gpart slot (plain stores)
    {
        const int c2 = tid >> 4, q2 = tid & 15;
        const int qh2 = q2 >> 3, j2 = q2 & 7;
        float S0 = 0.f, S1 = 0.f, S2 = 0.f;
        #pragma unroll
        for (int wvi = 0; wvi < 8; ++wvi) {
            S0 += red_s[(wvi * 64 + c2) * 17];
            const float* sp = &red_s[(wvi * 64 + qh2 * 32 + c2) * 17];
            S1 += sp[1 + j2];
            S2 += sp[9 + j2];
        }
        float* po = gpart + (((size_t)t * 128 + n) * 6 + h) * 1088;
        po[tid] = S1;
        po[512 + tid] = S2;
        if (q2 == 0) po[1024 + c2] = S0;
    }
}

// Kernel 3: epilogue — finalize t=2 stats, write p_out / a_out / out.
__global__ __launch_bounds__(512)
void em_final_kernel(const float* __restrict__ gpart,
                     const float* __restrict__ beta_u,
                     const float* __restrict__ beta_a,
                     float* __restrict__ out)
{
    __shared__ float aout_s[32];
    const int n   = blockIdx.x;
    const int tid = threadIdx.x;           // 512
    const int c2 = tid >> 4, q2 = tid & 15;

    const float* pa = gpart + ((size_t)2 * 128 + n) * 6 * 1088;
    float S1 = 0.f, S2 = 0.f, S0 = 0.f;
    #pragma unroll
    for (int j = 0; j < 6; ++j) {
        S1 += pa[j * 1088 + tid];
        S2 += pa[j * 1088 + 512 + tid];
        S0 += pa[j * 1088 + 1024 + c2];
    }
    float invr = 1.0f / (S0 + EPSV);
    float w0  = S0 * invr;
    float m   = S1 * invr;
    float s2p = S2 * invr;
    float sig = s2p - m * m * (2.0f - w0);
    sig = fmaxf(sig + EPSV, 1e-4f);
    float hl = 0.5f * logf(sig);
    float shl = red_sum16(hl);
    if (q2 == 0) {
        float bu  = beta_u[c2];
        float cs  = (16.0f * bu + shl) * S0;
        float arg = LAMBDAV * (beta_a[c2] - cs);
        float ao  = 1.0f / (1.0f + expf(-arg));
        ao = fminf(fmaxf(ao, 1e-4f), 1.0f - 1e-4f);
        if (isnan(ao)) ao = 0.5f;
        aout_s[c2] = ao;
    }
    float mu = m;
    if (isnan(mu)) mu = 0.f;
    mu = fminf(fmaxf(mu, -10000.f), 10000.f);
    out[(size_t)n * 512 + tid] = mu;
    out[69632 + (size_t)n * 544 + tid] = mu;
    __syncthreads();
    if (tid < 32) {
        float ao = aout_s[tid];
        out[65536 + n * 32 + tid] = ao;
        out[69632 + n * 544 + 512 + tid] = ao;
    }
}

extern "C" void kernel_launch(void* const* d_in, const int* in_sizes, int n_in,
                              void* d_out, int out_size, void* d_ws, size_t ws_size,
                              hipStream_t stream) {
    const float* x  = (const float*)d_in[0];
    const float* w  = (const float*)d_in[1];
    const float* bu = (const float*)d_in[2];
    const float* ba = (const float*)d_in[3];
    float* out = (float*)d_out;
    __hip_bfloat16* v = (__hip_bfloat16*)d_ws;               // 37.7 MB
    float* gpart = (float*)((char*)d_ws + (40u << 20));      // [3][128][6][1088]
    float* gfct  = (float*)((char*)d_ws + (52u << 20));      // [128][288]
    const unsigned short* vv = (const unsigned short*)v;

    conv_v_kernel<<<dim3(576), dim3(256), 0, stream>>>(x, w, v);
    em_sweep_kernel<<<dim3(768), dim3(512), 0, stream>>>(x, vv, bu, ba, gpart, gfct, 0);
    em_sweep_kernel<<<dim3(768), dim3(512), 0, stream>>>(x, vv, bu, ba, gpart, gfct, 1);
    em_sweep_kernel<<<dim3(768), dim3(512), 0, stream>>>(x, vv, bu, ba, gpart, gfct, 2);
    em_final_kernel<<<dim3(128), dim3(512), 0, stream>>>(gpart, bu, ba, out);
}